// Round 2
// baseline (299.602 us; speedup 1.0000x reference)
//
#include <hip/hip_runtime.h>
#include <math.h>

#define D_MODEL 2048
#define NUM_EXP 64
#define TILE_T  128   // tokens per k1 block

// ---------------------------------------------------------------------------
// Kernel 1: split-K partial GEMM. partial[kb][token][expert] (fp32).
// Block: 256 threads = 4 waves. Tile: 128 tokens x 64 experts.
// Fragment: 4 tokens x 8 experts (32 fp32 acc).
// tx = lane%8 (expert group), ty = tid/8 (token group) -> x-addr depends only
// on ty (8-lane broadcast), W-addr only on tx. No LDS. Explicit double-buffer
// (named a0/b0, a1/b1 — static indexing) so next iteration's 12 loads are in
// flight during current FMAs.
// Grid: (N/128, KS) = 1024 blocks at KS=8 -> 16 waves/CU available.
// ---------------------------------------------------------------------------
template<int KC>
__global__ __launch_bounds__(256, 3)
void k1_partial_gemm(const float* __restrict__ x, const float* __restrict__ W,
                     float* __restrict__ partial, int N) {
    const int tid  = threadIdx.x;
    const int tx   = tid & 7;
    const int ty   = tid >> 3;            // 0..31
    const int tok0  = blockIdx.x * TILE_T + ty * 4;
    const int kbase = blockIdx.y * KC;

    const float4* xr[4];
    const float4* wr[8];
#pragma unroll
    for (int i = 0; i < 4; ++i)
        xr[i] = reinterpret_cast<const float4*>(x + (size_t)(tok0 + i) * D_MODEL + kbase);
#pragma unroll
    for (int j = 0; j < 8; ++j)
        wr[j] = reinterpret_cast<const float4*>(W + (size_t)(tx * 8 + j) * D_MODEL + kbase);

    float acc[4][8];
#pragma unroll
    for (int i = 0; i < 4; ++i)
#pragma unroll
        for (int j = 0; j < 8; ++j) acc[i][j] = 0.f;

    auto loadA = [&](float4 (&A)[4], int kc) {
#pragma unroll
        for (int i = 0; i < 4; ++i) A[i] = xr[i][kc];
    };
    auto loadB = [&](float4 (&B)[8], int kc) {
#pragma unroll
        for (int j = 0; j < 8; ++j) B[j] = wr[j][kc];
    };
    auto fma8 = [&](const float4 (&A)[4], const float4 (&B)[8]) {
#pragma unroll
        for (int i = 0; i < 4; ++i)
#pragma unroll
            for (int j = 0; j < 8; ++j) {
                acc[i][j] += A[i].x * B[j].x;
                acc[i][j] += A[i].y * B[j].y;
                acc[i][j] += A[i].z * B[j].z;
                acc[i][j] += A[i].w * B[j].w;
            }
    };

    constexpr int NK = KC / 4;            // float4 steps (even)
    float4 a0[4], b0[8], a1[4], b1[8];

    loadA(a0, 0); loadB(b0, 0);
    for (int kc = 0; kc < NK - 2; kc += 2) {
        loadA(a1, kc + 1); loadB(b1, kc + 1);
        fma8(a0, b0);
        loadA(a0, kc + 2); loadB(b0, kc + 2);
        fma8(a1, b1);
    }
    loadA(a1, NK - 1); loadB(b1, NK - 1);
    fma8(a0, b0);
    fma8(a1, b1);

    float* base = partial + ((size_t)blockIdx.y * N + tok0) * NUM_EXP + tx * 8;
#pragma unroll
    for (int i = 0; i < 4; ++i) {
        float4* p = reinterpret_cast<float4*>(base + (size_t)i * NUM_EXP);
        p[0] = make_float4(acc[i][0], acc[i][1], acc[i][2], acc[i][3]);
        p[1] = make_float4(acc[i][4], acc[i][5], acc[i][6], acc[i][7]);
    }
}

// ---------------------------------------------------------------------------
// Kernel 2: one wave per token (lane == expert). KS is compile-time so the
// partial-sum loads are 8 independent (one wait), summed in fixed order.
// Softmax + top-2 (lax.top_k tie rule: lower index wins) + per-block expert
// prob/count partials (no atomics -> deterministic).
// ---------------------------------------------------------------------------
template<int KS>
__global__ __launch_bounds__(256)
void k2_finalize(const float* __restrict__ partial, float* __restrict__ out,
                 float* __restrict__ p_part, float* __restrict__ f_part, int N) {
    const int lane = threadIdx.x & 63;
    const int wid  = threadIdx.x >> 6;
    const int gw   = blockIdx.x * 4 + wid;
    const int NW   = gridDim.x * 4;

    float pacc = 0.f, facc = 0.f;

    for (int t = gw; t < N; t += NW) {
        const float* base = partial + (size_t)t * NUM_EXP + lane;
        float v[KS];
#pragma unroll
        for (int ks = 0; ks < KS; ++ks)
            v[ks] = base[(size_t)ks * N * NUM_EXP];
        float logit = 0.f;
#pragma unroll
        for (int ks = 0; ks < KS; ++ks) logit += v[ks];

        float m = logit;
        for (int off = 32; off; off >>= 1) m = fmaxf(m, __shfl_xor(m, off));
        float p = __expf(logit - m);
        float S = p;
        for (int off = 32; off; off >>= 1) S += __shfl_xor(S, off);
        float prob = p / S;

        float bv = logit; int bi = lane;
        for (int off = 32; off; off >>= 1) {
            float ov = __shfl_xor(bv, off);
            int   oi = __shfl_xor(bi, off);
            if (ov > bv || (ov == bv && oi < bi)) { bv = ov; bi = oi; }
        }
        float cv = (lane == bi) ? -INFINITY : logit;
        int   ci = lane;
        for (int off = 32; off; off >>= 1) {
            float ov = __shfl_xor(cv, off);
            int   oi = __shfl_xor(ci, off);
            if (ov > cv || (ov == cv && oi < ci)) { cv = ov; ci = oi; }
        }

        if (lane == 0) {
            float w0 = 1.f / (1.f + __expf(cv - bv));
            out[(size_t)t * 2]     = w0;
            out[(size_t)t * 2 + 1] = 1.f - w0;
            out[(size_t)2 * N + t * 2]     = (float)bi;
            out[(size_t)2 * N + t * 2 + 1] = (float)ci;
        }

        pacc += prob;
        facc += (lane == bi ? 1.f : 0.f) + (lane == ci ? 1.f : 0.f);
    }

    __shared__ float lp[4][64];
    __shared__ float lf[4][64];
    lp[wid][lane] = pacc;
    lf[wid][lane] = facc;
    __syncthreads();
    if (wid == 0) {
        float sp = lp[0][lane] + lp[1][lane] + lp[2][lane] + lp[3][lane];
        float sf = lf[0][lane] + lf[1][lane] + lf[2][lane] + lf[3][lane];
        p_part[(size_t)blockIdx.x * NUM_EXP + lane] = sp;
        f_part[(size_t)blockIdx.x * NUM_EXP + lane] = sf;
    }
}

// ---------------------------------------------------------------------------
// Kernel 3: deterministic aux-loss reduction, 16 waves.
// aux = E * sum_i (f_sum_i / N) * (p_sum_i / N)
// ---------------------------------------------------------------------------
__global__ __launch_bounds__(1024)
void k3_aux(const float* __restrict__ p_part, const float* __restrict__ f_part,
            float* __restrict__ out, int N, int B2) {
    const int lane = threadIdx.x & 63;
    const int wid  = threadIdx.x >> 6;    // 0..15
    float sp = 0.f, sf = 0.f;
    for (int b = wid; b < B2; b += 16) {
        sp += p_part[(size_t)b * NUM_EXP + lane];
        sf += f_part[(size_t)b * NUM_EXP + lane];
    }
    __shared__ float lsp[16][64];
    __shared__ float lsf[16][64];
    lsp[wid][lane] = sp;
    lsf[wid][lane] = sf;
    __syncthreads();
    if (wid == 0) {
        float tsp = 0.f, tsf = 0.f;
#pragma unroll
        for (int w = 0; w < 16; ++w) { tsp += lsp[w][lane]; tsf += lsf[w][lane]; }
        float v = tsp * tsf;
        for (int off = 32; off; off >>= 1) v += __shfl_xor(v, off);
        if (lane == 0)
            out[(size_t)4 * N] = (float)NUM_EXP * v / ((float)N * (float)N);
    }
}

extern "C" void kernel_launch(void* const* d_in, const int* in_sizes, int n_in,
                              void* d_out, int out_size, void* d_ws, size_t ws_size,
                              hipStream_t stream) {
    const float* x = (const float*)d_in[0];
    const float* W = (const float*)d_in[1];
    float* out = (float*)d_out;

    const int N = in_sizes[0] / D_MODEL;   // 16384

    const int B2 = 1024;                   // kernel-2 block count
    const size_t acc_bytes = (size_t)B2 * NUM_EXP * sizeof(float) * 2;

    int KS = 1;
    if      ((size_t)8 * N * NUM_EXP * 4 + acc_bytes <= ws_size) KS = 8;
    else if ((size_t)4 * N * NUM_EXP * 4 + acc_bytes <= ws_size) KS = 4;
    else if ((size_t)2 * N * NUM_EXP * 4 + acc_bytes <= ws_size) KS = 2;

    float* partial = (float*)d_ws;
    float* p_part  = partial + (size_t)KS * N * NUM_EXP;
    float* f_part  = p_part + (size_t)B2 * NUM_EXP;

    dim3 g1(N / TILE_T, KS), b1(256);
    switch (KS) {
        case 8:  k1_partial_gemm<256 ><<<g1, b1, 0, stream>>>(x, W, partial, N); break;
        case 4:  k1_partial_gemm<512 ><<<g1, b1, 0, stream>>>(x, W, partial, N); break;
        case 2:  k1_partial_gemm<1024><<<g1, b1, 0, stream>>>(x, W, partial, N); break;
        default: k1_partial_gemm<2048><<<g1, b1, 0, stream>>>(x, W, partial, N); break;
    }
    switch (KS) {
        case 8:  k2_finalize<8><<<B2, 256, 0, stream>>>(partial, out, p_part, f_part, N); break;
        case 4:  k2_finalize<4><<<B2, 256, 0, stream>>>(partial, out, p_part, f_part, N); break;
        case 2:  k2_finalize<2><<<B2, 256, 0, stream>>>(partial, out, p_part, f_part, N); break;
        default: k2_finalize<1><<<B2, 256, 0, stream>>>(partial, out, p_part, f_part, N); break;
    }
    k3_aux<<<1, 1024, 0, stream>>>(p_part, f_part, out, N, B2);
}

// Round 3
// 189.105 us; speedup vs baseline: 1.5843x; 1.5843x over previous
//
#include <hip/hip_runtime.h>
#include <math.h>

#define D_MODEL 2048
#define NUM_EXP 64

// ---------------------------------------------------------------------------
// Kernel 1: split-K partial GEMM. partial[kb][token][expert] (fp32).
// R1 structure restored: 256 threads = 4 waves, tile 256 tokens x 64 experts,
// fragment 8 tokens x 8 experts (64 acc), compiler-scheduled unroll-2 k-loop,
// 116 VGPR -> 4 waves/SIMD permitted. Occupancy now supplied by KS=16:
// grid = (N/256, 16) = 1024 blocks x 4 waves = 4096 waves = 4/SIMD.
// tx = lane%8 (expert group), ty = tid/8 (token group): x-addr depends only
// on ty (8-lane dedup), W-addr only on tx. No LDS.
// ---------------------------------------------------------------------------
template<int KC>
__global__ __launch_bounds__(256, 2)
void k1_partial_gemm(const float* __restrict__ x, const float* __restrict__ W,
                     float* __restrict__ partial, int N) {
    const int tid  = threadIdx.x;
    const int tx   = tid & 7;         // expert group: experts tx*8 .. tx*8+7
    const int ty   = tid >> 3;        // token group: 0..31
    const int tok0  = blockIdx.x * 256 + ty * 8;
    const int kbase = blockIdx.y * KC;

    const float4* xr[8];
    const float4* wr[8];
#pragma unroll
    for (int i = 0; i < 8; ++i)
        xr[i] = reinterpret_cast<const float4*>(x + (size_t)(tok0 + i) * D_MODEL + kbase);
#pragma unroll
    for (int j = 0; j < 8; ++j)
        wr[j] = reinterpret_cast<const float4*>(W + (size_t)(tx * 8 + j) * D_MODEL + kbase);

    float acc[8][8];
#pragma unroll
    for (int i = 0; i < 8; ++i)
#pragma unroll
        for (int j = 0; j < 8; ++j) acc[i][j] = 0.f;

#pragma unroll 2
    for (int kc = 0; kc < KC / 4; ++kc) {
        float4 a[8], b[8];
#pragma unroll
        for (int i = 0; i < 8; ++i) a[i] = xr[i][kc];
#pragma unroll
        for (int j = 0; j < 8; ++j) b[j] = wr[j][kc];
#pragma unroll
        for (int i = 0; i < 8; ++i) {
#pragma unroll
            for (int j = 0; j < 8; ++j) {
                acc[i][j] += a[i].x * b[j].x;
                acc[i][j] += a[i].y * b[j].y;
                acc[i][j] += a[i].z * b[j].z;
                acc[i][j] += a[i].w * b[j].w;
            }
        }
    }

    // partial[kb][token][expert]
    float* base = partial + ((size_t)blockIdx.y * N + tok0) * NUM_EXP + tx * 8;
#pragma unroll
    for (int i = 0; i < 8; ++i) {
        float4* p = reinterpret_cast<float4*>(base + (size_t)i * NUM_EXP);
        p[0] = make_float4(acc[i][0], acc[i][1], acc[i][2], acc[i][3]);
        p[1] = make_float4(acc[i][4], acc[i][5], acc[i][6], acc[i][7]);
    }
}

// ---------------------------------------------------------------------------
// Kernel 2: one wave per token-group (lane == expert). KS compile-time so the
// partial-sum loads are KS independent dwords (one wait), summed in fixed
// order (deterministic). Softmax + top-2 (lax.top_k tie rule: lower index
// wins) + per-block expert prob/count partials (no atomics).
// ---------------------------------------------------------------------------
template<int KS>
__global__ __launch_bounds__(256)
void k2_finalize(const float* __restrict__ partial, float* __restrict__ out,
                 float* __restrict__ p_part, float* __restrict__ f_part, int N) {
    const int lane = threadIdx.x & 63;
    const int wid  = threadIdx.x >> 6;
    const int gw   = blockIdx.x * 4 + wid;
    const int NW   = gridDim.x * 4;

    float pacc = 0.f, facc = 0.f;

    for (int t = gw; t < N; t += NW) {
        const float* base = partial + (size_t)t * NUM_EXP + lane;
        float v[KS];
#pragma unroll
        for (int ks = 0; ks < KS; ++ks)
            v[ks] = base[(size_t)ks * N * NUM_EXP];
        float logit = 0.f;
#pragma unroll
        for (int ks = 0; ks < KS; ++ks) logit += v[ks];

        float m = logit;
        for (int off = 32; off; off >>= 1) m = fmaxf(m, __shfl_xor(m, off));
        float p = __expf(logit - m);
        float S = p;
        for (int off = 32; off; off >>= 1) S += __shfl_xor(S, off);
        float prob = p / S;

        float bv = logit; int bi = lane;
        for (int off = 32; off; off >>= 1) {
            float ov = __shfl_xor(bv, off);
            int   oi = __shfl_xor(bi, off);
            if (ov > bv || (ov == bv && oi < bi)) { bv = ov; bi = oi; }
        }
        float cv = (lane == bi) ? -INFINITY : logit;
        int   ci = lane;
        for (int off = 32; off; off >>= 1) {
            float ov = __shfl_xor(cv, off);
            int   oi = __shfl_xor(ci, off);
            if (ov > cv || (ov == cv && oi < ci)) { cv = ov; ci = oi; }
        }

        if (lane == 0) {
            float w0 = 1.f / (1.f + __expf(cv - bv));
            out[(size_t)t * 2]     = w0;
            out[(size_t)t * 2 + 1] = 1.f - w0;
            out[(size_t)2 * N + t * 2]     = (float)bi;
            out[(size_t)2 * N + t * 2 + 1] = (float)ci;
        }

        pacc += prob;
        facc += (lane == bi ? 1.f : 0.f) + (lane == ci ? 1.f : 0.f);
    }

    __shared__ float lp[4][64];
    __shared__ float lf[4][64];
    lp[wid][lane] = pacc;
    lf[wid][lane] = facc;
    __syncthreads();
    if (wid == 0) {
        float sp = lp[0][lane] + lp[1][lane] + lp[2][lane] + lp[3][lane];
        float sf = lf[0][lane] + lf[1][lane] + lf[2][lane] + lf[3][lane];
        p_part[(size_t)blockIdx.x * NUM_EXP + lane] = sp;
        f_part[(size_t)blockIdx.x * NUM_EXP + lane] = sf;
    }
}

// ---------------------------------------------------------------------------
// Kernel 3: deterministic aux-loss reduction, 16 waves.
// aux = E * sum_i (f_sum_i / N) * (p_sum_i / N)
// ---------------------------------------------------------------------------
__global__ __launch_bounds__(1024)
void k3_aux(const float* __restrict__ p_part, const float* __restrict__ f_part,
            float* __restrict__ out, int N, int B2) {
    const int lane = threadIdx.x & 63;
    const int wid  = threadIdx.x >> 6;    // 0..15
    float sp = 0.f, sf = 0.f;
    for (int b = wid; b < B2; b += 16) {
        sp += p_part[(size_t)b * NUM_EXP + lane];
        sf += f_part[(size_t)b * NUM_EXP + lane];
    }
    __shared__ float lsp[16][64];
    __shared__ float lsf[16][64];
    lsp[wid][lane] = sp;
    lsf[wid][lane] = sf;
    __syncthreads();
    if (wid == 0) {
        float tsp = 0.f, tsf = 0.f;
#pragma unroll
        for (int w = 0; w < 16; ++w) { tsp += lsp[w][lane]; tsf += lsf[w][lane]; }
        float v = tsp * tsf;
        for (int off = 32; off; off >>= 1) v += __shfl_xor(v, off);
        if (lane == 0)
            out[(size_t)4 * N] = (float)NUM_EXP * v / ((float)N * (float)N);
    }
}

extern "C" void kernel_launch(void* const* d_in, const int* in_sizes, int n_in,
                              void* d_out, int out_size, void* d_ws, size_t ws_size,
                              hipStream_t stream) {
    const float* x = (const float*)d_in[0];
    const float* W = (const float*)d_in[1];
    float* out = (float*)d_out;

    const int N = in_sizes[0] / D_MODEL;   // 16384

    const int B2 = 1024;                   // kernel-2 block count
    const size_t acc_bytes = (size_t)B2 * NUM_EXP * sizeof(float) * 2;

    // split-K factor: as large as workspace allows (more waves -> latency hiding)
    int KS = 1;
    if      ((size_t)16 * N * NUM_EXP * 4 + acc_bytes <= ws_size) KS = 16;
    else if ((size_t)8  * N * NUM_EXP * 4 + acc_bytes <= ws_size) KS = 8;
    else if ((size_t)4  * N * NUM_EXP * 4 + acc_bytes <= ws_size) KS = 4;
    else if ((size_t)2  * N * NUM_EXP * 4 + acc_bytes <= ws_size) KS = 2;

    float* partial = (float*)d_ws;
    float* p_part  = partial + (size_t)KS * N * NUM_EXP;
    float* f_part  = p_part + (size_t)B2 * NUM_EXP;

    dim3 g1(N / 256, KS), b1(256);
    switch (KS) {
        case 16: k1_partial_gemm<128 ><<<g1, b1, 0, stream>>>(x, W, partial, N); break;
        case 8:  k1_partial_gemm<256 ><<<g1, b1, 0, stream>>>(x, W, partial, N); break;
        case 4:  k1_partial_gemm<512 ><<<g1, b1, 0, stream>>>(x, W, partial, N); break;
        case 2:  k1_partial_gemm<1024><<<g1, b1, 0, stream>>>(x, W, partial, N); break;
        default: k1_partial_gemm<2048><<<g1, b1, 0, stream>>>(x, W, partial, N); break;
    }
    switch (KS) {
        case 16: k2_finalize<16><<<B2, 256, 0, stream>>>(partial, out, p_part, f_part, N); break;
        case 8:  k2_finalize<8 ><<<B2, 256, 0, stream>>>(partial, out, p_part, f_part, N); break;
        case 4:  k2_finalize<4 ><<<B2, 256, 0, stream>>>(partial, out, p_part, f_part, N); break;
        case 2:  k2_finalize<2 ><<<B2, 256, 0, stream>>>(partial, out, p_part, f_part, N); break;
        default: k2_finalize<1 ><<<B2, 256, 0, stream>>>(partial, out, p_part, f_part, N); break;
    }
    k3_aux<<<1, 1024, 0, stream>>>(p_part, f_part, out, N, B2);
}

// Round 4
// 70.891 us; speedup vs baseline: 4.2262x; 2.6675x over previous
//
#include <hip/hip_runtime.h>
#include <math.h>

#define D_MODEL 2048
#define NUM_EXP 64

typedef _Float16 f16x8 __attribute__((ext_vector_type(8)));
typedef float    f32x4 __attribute__((ext_vector_type(4)));

// ---------------------------------------------------------------------------
// k0: convert W[64][2048] fp32 -> fragment-linear f16 hi/lo buffers.
// Split: W = wh + wl * 2^-12, wl stored scaled by 4096 (stays fp16-normal).
// Fragment layout (A-operand of mfma_f32_16x16x32_f16, D = experts x tokens):
//   frag (kc, mf): lane l holds A[m = mf*16 + (l&15)][k = kc*32 + (l>>4)*8 + j]
//   stored flat at whf[(kc*4 + mf)*64 + l] -> k1's W-load is one coalesced
//   dwordx4 per lane (1 KB per wave-load), L2-resident.
// 16384 threads total: t enumerates (kc, mf, lane) exactly in layout order.
// ---------------------------------------------------------------------------
__global__ __launch_bounds__(256)
void k0_convw(const float* __restrict__ W, f16x8* __restrict__ whf,
              f16x8* __restrict__ wlf) {
    const int t    = blockIdx.x * 256 + threadIdx.x;   // 0..16383
    const int lane = t & 63;
    const int mf   = (t >> 6) & 3;
    const int kc   = t >> 8;                           // 0..63
    const int m    = mf * 16 + (lane & 15);
    const int k0   = kc * 32 + ((lane >> 4) << 3);
    const float* src = W + (size_t)m * D_MODEL + k0;
    f16x8 h, l;
#pragma unroll
    for (int j = 0; j < 8; ++j) {
        float v = src[j];
        _Float16 hh = (_Float16)v;                     // RTN
        h[j] = hh;
        l[j] = (_Float16)((v - (float)hh) * 4096.f);   // exact residual, scaled
    }
    whf[t] = h;
    wlf[t] = l;
}

// ---------------------------------------------------------------------------
// k1: logits^T = W * x^T via MFMA, split-K partials into partial[kb][tok][exp].
// Per wave: 16 tokens (one B-frag) x 64 experts (4 A-frags), CHUNKS k-steps
// of 32. x is the B-operand: lane reads x[tok0+(lane&15)][k+(lane>>4)*8+j],
// 8 contiguous fp32 = two float4 loads; converted in-register to f16 hi/lo.
// acc1 = xh*wh; acc2 = xh*wl' + xl'*wh (both scaled 2^12); out = acc1+acc2/4096.
// No LDS / no barriers: pure register dataflow, full unroll lets loads hoist.
// Grid: (N/64, KS). KS=4 -> 1024 blocks x 4 waves = 4096 waves.
// ---------------------------------------------------------------------------
template<int CHUNKS>
__global__ __launch_bounds__(256)
void k1_mfma(const float* __restrict__ x, const f16x8* __restrict__ whf,
             const f16x8* __restrict__ wlf, float* __restrict__ partial, int N) {
    const int lane = threadIdx.x & 63;
    const int wid  = threadIdx.x >> 6;
    const int tg   = blockIdx.x * 4 + wid;     // token-group (16 tokens)
    const int tok0 = tg * 16;
    const int kb   = blockIdx.y;

    const float* xrow =
        x + (size_t)(tok0 + (lane & 15)) * D_MODEL + ((lane >> 4) << 3);

    f32x4 acc1[4], acc2[4];
#pragma unroll
    for (int mf = 0; mf < 4; ++mf) {
        acc1[mf] = f32x4{0.f, 0.f, 0.f, 0.f};
        acc2[mf] = f32x4{0.f, 0.f, 0.f, 0.f};
    }

#pragma unroll
    for (int c = 0; c < CHUNKS; ++c) {
        const int kc = kb * CHUNKS + c;
        const float4 lo = *(const float4*)(xrow + (size_t)kc * 32);
        const float4 hi = *(const float4*)(xrow + (size_t)kc * 32 + 4);
        const float v[8] = {lo.x, lo.y, lo.z, lo.w, hi.x, hi.y, hi.z, hi.w};
        f16x8 xh, xl;
#pragma unroll
        for (int j = 0; j < 8; ++j) {
            _Float16 h = (_Float16)v[j];
            xh[j] = h;
            xl[j] = (_Float16)((v[j] - (float)h) * 4096.f);
        }
        const f16x8* wb = whf + (size_t)kc * 256 + lane;
        const f16x8* lb = wlf + (size_t)kc * 256 + lane;
#pragma unroll
        for (int mf = 0; mf < 4; ++mf) {
            const f16x8 wh = wb[mf * 64];
            const f16x8 wl = lb[mf * 64];
            acc1[mf] = __builtin_amdgcn_mfma_f32_16x16x32_f16(wh, xh, acc1[mf], 0, 0, 0);
            acc2[mf] = __builtin_amdgcn_mfma_f32_16x16x32_f16(wh, xl, acc2[mf], 0, 0, 0);
            acc2[mf] = __builtin_amdgcn_mfma_f32_16x16x32_f16(wl, xh, acc2[mf], 0, 0, 0);
        }
    }

    // C layout: col = lane&15 = token, row = (lane>>4)*4 + r = expert (in mf*16)
    float* base = partial + ((size_t)kb * N + tok0 + (lane & 15)) * NUM_EXP
                + ((lane >> 4) << 2);
#pragma unroll
    for (int mf = 0; mf < 4; ++mf) {
        float4 o;
        o.x = acc1[mf].x + acc2[mf].x * (1.f / 4096.f);
        o.y = acc1[mf].y + acc2[mf].y * (1.f / 4096.f);
        o.z = acc1[mf].z + acc2[mf].z * (1.f / 4096.f);
        o.w = acc1[mf].w + acc2[mf].w * (1.f / 4096.f);
        *(float4*)(base + mf * 16) = o;
    }
}

// ---------------------------------------------------------------------------
// k2: one wave per token (lane == expert). KS compile-time -> independent
// loads, fixed-order sum (deterministic). Softmax + top-2 (lower index wins
// on ties, matching lax.top_k) + per-block expert prob/count partials.
// ---------------------------------------------------------------------------
template<int KS>
__global__ __launch_bounds__(256)
void k2_finalize(const float* __restrict__ partial, float* __restrict__ out,
                 float* __restrict__ p_part, float* __restrict__ f_part, int N) {
    const int lane = threadIdx.x & 63;
    const int wid  = threadIdx.x >> 6;
    const int gw   = blockIdx.x * 4 + wid;
    const int NW   = gridDim.x * 4;

    float pacc = 0.f, facc = 0.f;

    for (int t = gw; t < N; t += NW) {
        const float* base = partial + (size_t)t * NUM_EXP + lane;
        float v[KS];
#pragma unroll
        for (int ks = 0; ks < KS; ++ks)
            v[ks] = base[(size_t)ks * N * NUM_EXP];
        float logit = 0.f;
#pragma unroll
        for (int ks = 0; ks < KS; ++ks) logit += v[ks];

        float m = logit;
        for (int off = 32; off; off >>= 1) m = fmaxf(m, __shfl_xor(m, off));
        float p = __expf(logit - m);
        float S = p;
        for (int off = 32; off; off >>= 1) S += __shfl_xor(S, off);
        float prob = p / S;

        float bv = logit; int bi = lane;
        for (int off = 32; off; off >>= 1) {
            float ov = __shfl_xor(bv, off);
            int   oi = __shfl_xor(bi, off);
            if (ov > bv || (ov == bv && oi < bi)) { bv = ov; bi = oi; }
        }
        float cv = (lane == bi) ? -INFINITY : logit;
        int   ci = lane;
        for (int off = 32; off; off >>= 1) {
            float ov = __shfl_xor(cv, off);
            int   oi = __shfl_xor(ci, off);
            if (ov > cv || (ov == cv && oi < ci)) { cv = ov; ci = oi; }
        }

        if (lane == 0) {
            float w0 = 1.f / (1.f + __expf(cv - bv));
            out[(size_t)t * 2]     = w0;
            out[(size_t)t * 2 + 1] = 1.f - w0;
            out[(size_t)2 * N + t * 2]     = (float)bi;
            out[(size_t)2 * N + t * 2 + 1] = (float)ci;
        }

        pacc += prob;
        facc += (lane == bi ? 1.f : 0.f) + (lane == ci ? 1.f : 0.f);
    }

    __shared__ float lp[4][64];
    __shared__ float lf[4][64];
    lp[wid][lane] = pacc;
    lf[wid][lane] = facc;
    __syncthreads();
    if (wid == 0) {
        float sp = lp[0][lane] + lp[1][lane] + lp[2][lane] + lp[3][lane];
        float sf = lf[0][lane] + lf[1][lane] + lf[2][lane] + lf[3][lane];
        p_part[(size_t)blockIdx.x * NUM_EXP + lane] = sp;
        f_part[(size_t)blockIdx.x * NUM_EXP + lane] = sf;
    }
}

// ---------------------------------------------------------------------------
// k3: deterministic aux-loss reduction.
// aux = E * sum_i (f_sum_i / N) * (p_sum_i / N)
// ---------------------------------------------------------------------------
__global__ __launch_bounds__(1024)
void k3_aux(const float* __restrict__ p_part, const float* __restrict__ f_part,
            float* __restrict__ out, int N, int B2) {
    const int lane = threadIdx.x & 63;
    const int wid  = threadIdx.x >> 6;    // 0..15
    float sp = 0.f, sf = 0.f;
    for (int b = wid; b < B2; b += 16) {
        sp += p_part[(size_t)b * NUM_EXP + lane];
        sf += f_part[(size_t)b * NUM_EXP + lane];
    }
    __shared__ float lsp[16][64];
    __shared__ float lsf[16][64];
    lsp[wid][lane] = sp;
    lsf[wid][lane] = sf;
    __syncthreads();
    if (wid == 0) {
        float tsp = 0.f, tsf = 0.f;
#pragma unroll
        for (int w = 0; w < 16; ++w) { tsp += lsp[w][lane]; tsf += lsf[w][lane]; }
        float v = tsp * tsf;
        for (int off = 32; off; off >>= 1) v += __shfl_xor(v, off);
        if (lane == 0)
            out[(size_t)4 * N] = (float)NUM_EXP * v / ((float)N * (float)N);
    }
}

extern "C" void kernel_launch(void* const* d_in, const int* in_sizes, int n_in,
                              void* d_out, int out_size, void* d_ws, size_t ws_size,
                              hipStream_t stream) {
    const float* x = (const float*)d_in[0];
    const float* W = (const float*)d_in[1];
    float* out = (float*)d_out;

    const int N = in_sizes[0] / D_MODEL;   // 16384
    const int B2 = 1024;                   // k2 block count

    // ws layout: [whf 256KB][wlf 256KB][partial KS*N*64*4][p_part][f_part]
    f16x8* whf = (f16x8*)d_ws;
    f16x8* wlf = whf + 16384;
    float* partial = (float*)(wlf + 16384);
    const size_t fixed = (size_t)2 * 16384 * sizeof(f16x8)
                       + (size_t)B2 * NUM_EXP * sizeof(float) * 2;

    int KS = 1;
    if      ((size_t)4 * N * NUM_EXP * 4 + fixed <= ws_size) KS = 4;
    else if ((size_t)2 * N * NUM_EXP * 4 + fixed <= ws_size) KS = 2;

    float* p_part = partial + (size_t)KS * N * NUM_EXP;
    float* f_part = p_part + (size_t)B2 * NUM_EXP;

    k0_convw<<<64, 256, 0, stream>>>(W, whf, wlf);

    dim3 g1(N / 64, KS), b1(256);
    switch (KS) {
        case 4:  k1_mfma<16><<<g1, b1, 0, stream>>>(x, whf, wlf, partial, N); break;
        case 2:  k1_mfma<32><<<g1, b1, 0, stream>>>(x, whf, wlf, partial, N); break;
        default: k1_mfma<64><<<g1, b1, 0, stream>>>(x, whf, wlf, partial, N); break;
    }
    switch (KS) {
        case 4:  k2_finalize<4><<<B2, 256, 0, stream>>>(partial, out, p_part, f_part, N); break;
        case 2:  k2_finalize<2><<<B2, 256, 0, stream>>>(partial, out, p_part, f_part, N); break;
        default: k2_finalize<1><<<B2, 256, 0, stream>>>(partial, out, p_part, f_part, N); break;
    }
    k3_aux<<<1, 1024, 0, stream>>>(p_part, f_part, out, N, B2);
}

// Round 5
// 69.760 us; speedup vs baseline: 4.2947x; 1.0162x over previous
//
#include <hip/hip_runtime.h>
#include <math.h>

#define D_MODEL 2048
#define NUM_EXP 64

typedef _Float16 f16x8 __attribute__((ext_vector_type(8)));
typedef float    f32x4 __attribute__((ext_vector_type(4)));

// ---------------------------------------------------------------------------
// k0: convert W[64][2048] fp32 -> fragment-linear f16 hi/lo buffers.
// Split: W = wh + wl * 2^-12, wl stored scaled by 4096 (fp16-normal range).
// Fragment layout (A-operand of mfma_f32_16x16x32_f16, D = experts x tokens):
//   frag (kc, mf): lane l holds A[m = mf*16 + (l&15)][k = kc*32 + (l>>4)*8 + j]
//   stored flat at whf[(kc*4 + mf)*64 + l] -> k1's W-load is one coalesced
//   dwordx4 per lane (1 KB per wave-load), L2-resident.
// ---------------------------------------------------------------------------
__global__ __launch_bounds__(256)
void k0_convw(const float* __restrict__ W, f16x8* __restrict__ whf,
              f16x8* __restrict__ wlf) {
    const int t    = blockIdx.x * 256 + threadIdx.x;   // 0..16383
    const int lane = t & 63;
    const int mf   = (t >> 6) & 3;
    const int kc   = t >> 8;                           // 0..63
    const int m    = mf * 16 + (lane & 15);
    const int k0   = kc * 32 + ((lane >> 4) << 3);
    const float* src = W + (size_t)m * D_MODEL + k0;
    f16x8 h, l;
#pragma unroll
    for (int j = 0; j < 8; ++j) {
        float v = src[j];
        _Float16 hh = (_Float16)v;
        h[j] = hh;
        l[j] = (_Float16)((v - (float)hh) * 4096.f);   // exact residual, scaled
    }
    whf[t] = h;
    wlf[t] = l;
}

// ---------------------------------------------------------------------------
// k1: fully fused. One block = 4 waves = 16 tokens x full K.
// Wave wid computes K-slice [wid*512, wid*512+512) into 2 fp32 accumulators
// via 3 MFMA/chunk (xh*wh, xh*wl, xl*wh; low terms scaled 2^12).
// Epilogue: partial C -> XOR-swizzled LDS tile -> each wave reduces 4 K-slices
// and runs softmax + top-2 (lax.top_k tie rule: lower index wins) for 4
// tokens, writing weights/indices + per-block expert prob/count partials.
// No partial-logits global round-trip. All sums fixed-order (deterministic).
// Grid: N/16 = 1024 blocks x 4 waves = 4096 waves (4/SIMD).
// ---------------------------------------------------------------------------
__global__ __launch_bounds__(256)
void k1_fused(const float* __restrict__ x, const f16x8* __restrict__ whf,
              const f16x8* __restrict__ wlf, float* __restrict__ out,
              float* __restrict__ p_part, float* __restrict__ f_part, int N) {
    const int lane = threadIdx.x & 63;
    const int wid  = threadIdx.x >> 6;          // K-slice 0..3
    const int tok0 = blockIdx.x * 16;

    const float* xrow =
        x + (size_t)(tok0 + (lane & 15)) * D_MODEL + ((lane >> 4) << 3);

    f32x4 acc1[4], acc2[4];
#pragma unroll
    for (int mf = 0; mf < 4; ++mf) {
        acc1[mf] = f32x4{0.f, 0.f, 0.f, 0.f};
        acc2[mf] = f32x4{0.f, 0.f, 0.f, 0.f};
    }

#pragma unroll
    for (int c = 0; c < 16; ++c) {
        const int kc = wid * 16 + c;            // chunk of 32 k-values
        const float4 lo = *(const float4*)(xrow + (size_t)kc * 32);
        const float4 hi = *(const float4*)(xrow + (size_t)kc * 32 + 4);
        const float v[8] = {lo.x, lo.y, lo.z, lo.w, hi.x, hi.y, hi.z, hi.w};
        f16x8 xh, xl;
#pragma unroll
        for (int j = 0; j < 8; ++j) {
            _Float16 h = (_Float16)v[j];
            xh[j] = h;
            xl[j] = (_Float16)((v[j] - (float)h) * 4096.f);
        }
        const f16x8* wb = whf + (size_t)kc * 256 + lane;
        const f16x8* lb = wlf + (size_t)kc * 256 + lane;
#pragma unroll
        for (int mf = 0; mf < 4; ++mf) {
            const f16x8 wh = wb[mf * 64];
            const f16x8 wl = lb[mf * 64];
            acc1[mf] = __builtin_amdgcn_mfma_f32_16x16x32_f16(wh, xh, acc1[mf], 0, 0, 0);
            acc2[mf] = __builtin_amdgcn_mfma_f32_16x16x32_f16(wh, xl, acc2[mf], 0, 0, 0);
            acc2[mf] = __builtin_amdgcn_mfma_f32_16x16x32_f16(wl, xh, acc2[mf], 0, 0, 0);
        }
    }

    // --- stage per-wave partial C into LDS (XOR-swizzled) ------------------
    // C layout: col = lane&15 = token, row = (lane>>4)*4 + r within mf*16.
    // Float-index swizzle: fidx ^= (tok&7)<<2 (byte bits 4-6) -> write <=4-way
    // (once), read conflict-free.
    __shared__ float lds[4 * 16 * 64];
    __shared__ float p_red[4][64];
    __shared__ float f_red[4][64];

    const int tok = lane & 15;
#pragma unroll
    for (int mf = 0; mf < 4; ++mf) {
        const int exp0 = mf * 16 + ((lane >> 4) << 2);
        const int fidx = wid * 1024 + tok * 64 + (exp0 ^ ((tok & 7) << 2));
        f32x4 o = acc1[mf] + acc2[mf] * (1.f / 4096.f);
        *(f32x4*)&lds[fidx] = o;
    }
    __syncthreads();

    // --- reduce 4 K-slices + softmax + top-2, 4 tokens per wave ------------
    float pacc = 0.f, facc = 0.f;
#pragma unroll
    for (int i = 0; i < 4; ++i) {
        const int t   = wid * 4 + i;
        const int rix = t * 64 + (lane ^ ((t & 7) << 2));
        float logit = lds[rix] + lds[1024 + rix] + lds[2048 + rix] + lds[3072 + rix];

        float m = logit;
        for (int off = 32; off; off >>= 1) m = fmaxf(m, __shfl_xor(m, off));
        float p = __expf(logit - m);
        float S = p;
        for (int off = 32; off; off >>= 1) S += __shfl_xor(S, off);
        float prob = p / S;

        float bv = logit; int bi = lane;
        for (int off = 32; off; off >>= 1) {
            float ov = __shfl_xor(bv, off);
            int   oi = __shfl_xor(bi, off);
            if (ov > bv || (ov == bv && oi < bi)) { bv = ov; bi = oi; }
        }
        float cv = (lane == bi) ? -INFINITY : logit;
        int   ci = lane;
        for (int off = 32; off; off >>= 1) {
            float ov = __shfl_xor(cv, off);
            int   oi = __shfl_xor(ci, off);
            if (ov > cv || (ov == cv && oi < ci)) { cv = ov; ci = oi; }
        }

        if (lane == 0) {
            const int gt = tok0 + t;
            float w0 = 1.f / (1.f + __expf(cv - bv));
            out[(size_t)gt * 2]     = w0;
            out[(size_t)gt * 2 + 1] = 1.f - w0;
            out[(size_t)2 * N + gt * 2]     = (float)bi;
            out[(size_t)2 * N + gt * 2 + 1] = (float)ci;
        }

        pacc += prob;
        facc += (lane == bi ? 1.f : 0.f) + (lane == ci ? 1.f : 0.f);
    }

    p_red[wid][lane] = pacc;
    f_red[wid][lane] = facc;
    __syncthreads();
    if (wid == 0) {
        float sp = p_red[0][lane] + p_red[1][lane] + p_red[2][lane] + p_red[3][lane];
        float sf = f_red[0][lane] + f_red[1][lane] + f_red[2][lane] + f_red[3][lane];
        p_part[(size_t)blockIdx.x * NUM_EXP + lane] = sp;
        f_part[(size_t)blockIdx.x * NUM_EXP + lane] = sf;
    }
}

// ---------------------------------------------------------------------------
// k3: deterministic aux-loss reduction over 1024 per-block partials.
// aux = E * sum_i (f_sum_i / N) * (p_sum_i / N)
// ---------------------------------------------------------------------------
__global__ __launch_bounds__(1024)
void k3_aux(const float* __restrict__ p_part, const float* __restrict__ f_part,
            float* __restrict__ out, int N, int B2) {
    const int lane = threadIdx.x & 63;
    const int wid  = threadIdx.x >> 6;    // 0..15
    float sp = 0.f, sf = 0.f;
    for (int b = wid; b < B2; b += 16) {
        sp += p_part[(size_t)b * NUM_EXP + lane];
        sf += f_part[(size_t)b * NUM_EXP + lane];
    }
    __shared__ float lsp[16][64];
    __shared__ float lsf[16][64];
    lsp[wid][lane] = sp;
    lsf[wid][lane] = sf;
    __syncthreads();
    if (wid == 0) {
        float tsp = 0.f, tsf = 0.f;
#pragma unroll
        for (int w = 0; w < 16; ++w) { tsp += lsp[w][lane]; tsf += lsf[w][lane]; }
        float v = tsp * tsf;
        for (int off = 32; off; off >>= 1) v += __shfl_xor(v, off);
        if (lane == 0)
            out[(size_t)4 * N] = (float)NUM_EXP * v / ((float)N * (float)N);
    }
}

extern "C" void kernel_launch(void* const* d_in, const int* in_sizes, int n_in,
                              void* d_out, int out_size, void* d_ws, size_t ws_size,
                              hipStream_t stream) {
    const float* x = (const float*)d_in[0];
    const float* W = (const float*)d_in[1];
    float* out = (float*)d_out;

    const int N  = in_sizes[0] / D_MODEL;   // 16384
    const int B1 = N / 16;                  // 1024 fused blocks

    // ws layout: [whf 256KB][wlf 256KB][p_part 256KB][f_part 256KB]
    f16x8* whf = (f16x8*)d_ws;
    f16x8* wlf = whf + 16384;
    float* p_part = (float*)(wlf + 16384);
    float* f_part = p_part + (size_t)B1 * NUM_EXP;

    k0_convw<<<64, 256, 0, stream>>>(W, whf, wlf);
    k1_fused<<<B1, 256, 0, stream>>>(x, whf, wlf, out, p_part, f_part, N);
    k3_aux<<<1, 1024, 0, stream>>>(p_part, f_part, out, N, B1);
}

// Round 6
// 50.594 us; speedup vs baseline: 5.9217x; 1.3788x over previous
//
#include <hip/hip_runtime.h>
#include <math.h>

#define D_MODEL 2048
#define NUM_EXP 64

typedef _Float16 f16x8 __attribute__((ext_vector_type(8)));
typedef float    f32x4 __attribute__((ext_vector_type(4)));

// ---------------------------------------------------------------------------
// k0: convert W[64][2048] fp32 -> fragment-linear f16 hi/lo buffers.
// Split: W = wh + wl * 2^-12, wl stored scaled by 4096 (fp16-normal range).
// Fragment layout (A-operand of mfma_f32_16x16x32_f16):
//   frag (kc, mf): lane l holds A[m = mf*16 + (l&15)][k = kc*32 + (l>>4)*8 + j]
//   stored flat at whf[(kc*4 + mf)*64 + l] -> k1's W-load is one coalesced
//   dwordx4 per lane (1 KB per wave-load), L2-resident.
// ---------------------------------------------------------------------------
__global__ __launch_bounds__(256)
void k0_convw(const float* __restrict__ W, f16x8* __restrict__ whf,
              f16x8* __restrict__ wlf) {
    const int t    = blockIdx.x * 256 + threadIdx.x;   // 0..16383
    const int lane = t & 63;
    const int mf   = (t >> 6) & 3;
    const int kc   = t >> 8;                           // 0..63
    const int m    = mf * 16 + (lane & 15);
    const int k0   = kc * 32 + ((lane >> 4) << 3);
    const float* src = W + (size_t)m * D_MODEL + k0;
    f16x8 h, l;
#pragma unroll
    for (int j = 0; j < 8; ++j) {
        float v = src[j];
        _Float16 hh = (_Float16)v;
        h[j] = hh;
        l[j] = (_Float16)((v - (float)hh) * 4096.f);   // exact residual, scaled
    }
    whf[t] = h;
    wlf[t] = l;
}

// ---------------------------------------------------------------------------
// k1: fully fused router. Block = 8 waves (512 thr) = 64 tokens x full K.
// Wave wid computes K-slice [wid*256, wid*256+256) for all 64 tokens x 64
// experts: per 32-k chunk, 8 W-frag loads feed 48 MFMAs (4 token-frags x
// 4 expert-frags x 3 passes of the exact fp16 split:
//   logits = xh*wh + 2^-12*(xh*wl + xl*wh),  low terms stored scaled 2^12).
// Full unroll (8 chunks) + 256-VGPR budget -> loads of chunk c+1 hoist into
// chunk c's MFMA block (this was R5's failure at VGPR=60).
// Epilogue: 8 K-slice partials -> XOR-swizzled 128KB LDS tile -> each wave
// reduces 8 tokens (fixed order), softmax + top-2 (lax.top_k tie rule:
// lower index wins), writes weights/indices + per-block expert partials.
// Grid: N/64 = 256 blocks; 1 block/CU (LDS-bound), 8 waves/CU.
// ---------------------------------------------------------------------------
__global__ __launch_bounds__(512, 2)
void k1_fused(const float* __restrict__ x, const f16x8* __restrict__ whf,
              const f16x8* __restrict__ wlf, float* __restrict__ out,
              float* __restrict__ p_part, float* __restrict__ f_part, int N) {
    const int lane = threadIdx.x & 63;
    const int wid  = threadIdx.x >> 6;          // K-slice 0..7
    const int tok0 = blockIdx.x * 64;

    // x row base for each token-frag: lane&15 selects token, lane>>4 the
    // 8-float k-segment within a 32-k chunk.
    const float* xrow[4];
#pragma unroll
    for (int tf = 0; tf < 4; ++tf)
        xrow[tf] = x + (size_t)(tok0 + tf * 16 + (lane & 15)) * D_MODEL
                 + ((lane >> 4) << 3);

    f32x4 acc1[4][4], acc2[4][4];               // [tf][mf]
#pragma unroll
    for (int tf = 0; tf < 4; ++tf)
#pragma unroll
        for (int mf = 0; mf < 4; ++mf) {
            acc1[tf][mf] = f32x4{0.f, 0.f, 0.f, 0.f};
            acc2[tf][mf] = f32x4{0.f, 0.f, 0.f, 0.f};
        }

#pragma unroll
    for (int c = 0; c < 8; ++c) {
        const int kc = wid * 8 + c;             // global 32-k chunk
        // ---- hoisted loads: 8x W-frags + 8x x-float4 ----
        const f16x8* wb = whf + (size_t)kc * 256 + lane;
        const f16x8* lb = wlf + (size_t)kc * 256 + lane;
        f16x8 wh[4], wl[4];
#pragma unroll
        for (int mf = 0; mf < 4; ++mf) { wh[mf] = wb[mf * 64]; wl[mf] = lb[mf * 64]; }

        float4 xlo[4], xhi[4];
#pragma unroll
        for (int tf = 0; tf < 4; ++tf) {
            xlo[tf] = *(const float4*)(xrow[tf] + (size_t)kc * 32);
            xhi[tf] = *(const float4*)(xrow[tf] + (size_t)kc * 32 + 4);
        }

        // ---- convert x to exact fp16 hi/lo ----
        f16x8 xh[4], xl[4];
#pragma unroll
        for (int tf = 0; tf < 4; ++tf) {
            const float v[8] = {xlo[tf].x, xlo[tf].y, xlo[tf].z, xlo[tf].w,
                                xhi[tf].x, xhi[tf].y, xhi[tf].z, xhi[tf].w};
#pragma unroll
            for (int j = 0; j < 8; ++j) {
                _Float16 h = (_Float16)v[j];
                xh[tf][j] = h;
                xl[tf][j] = (_Float16)((v[j] - (float)h) * 4096.f);
            }
        }

        // ---- 48 MFMAs ----
#pragma unroll
        for (int tf = 0; tf < 4; ++tf)
#pragma unroll
            for (int mf = 0; mf < 4; ++mf) {
                acc1[tf][mf] = __builtin_amdgcn_mfma_f32_16x16x32_f16(
                    wh[mf], xh[tf], acc1[tf][mf], 0, 0, 0);
                acc2[tf][mf] = __builtin_amdgcn_mfma_f32_16x16x32_f16(
                    wh[mf], xl[tf], acc2[tf][mf], 0, 0, 0);
                acc2[tf][mf] = __builtin_amdgcn_mfma_f32_16x16x32_f16(
                    wl[mf], xh[tf], acc2[tf][mf], 0, 0, 0);
            }
    }

    // --- stage per-wave partial C into LDS (XOR-swizzled, bijective/token) --
    // C layout: col = lane&15 = token (in tf*16), row = (lane>>4)*4+r (in mf*16).
    __shared__ float lds[8 * 64 * 64];          // 128 KB
    __shared__ float p_red[8][64];
    __shared__ float f_red[8][64];

#pragma unroll
    for (int tf = 0; tf < 4; ++tf) {
        const int tl = tf * 16 + (lane & 15);
#pragma unroll
        for (int mf = 0; mf < 4; ++mf) {
            const int e0   = mf * 16 + ((lane >> 4) << 2);
            const int fidx = wid * 4096 + tl * 64 + (e0 ^ ((tl & 7) << 2));
            f32x4 o = acc1[tf][mf] + acc2[tf][mf] * (1.f / 4096.f);
            *(f32x4*)&lds[fidx] = o;
        }
    }
    __syncthreads();

    // --- reduce 8 K-slices + softmax + top-2, 8 tokens per wave -------------
    float pacc = 0.f, facc = 0.f;
#pragma unroll
    for (int i = 0; i < 8; ++i) {
        const int tl  = wid * 8 + i;
        const int rix = tl * 64 + (lane ^ ((tl & 7) << 2));
        float logit = 0.f;
#pragma unroll
        for (int s = 0; s < 8; ++s) logit += lds[s * 4096 + rix];

        float m = logit;
        for (int off = 32; off; off >>= 1) m = fmaxf(m, __shfl_xor(m, off));
        float p = __expf(logit - m);
        float S = p;
        for (int off = 32; off; off >>= 1) S += __shfl_xor(S, off);
        float prob = p / S;

        float bv = logit; int bi = lane;
        for (int off = 32; off; off >>= 1) {
            float ov = __shfl_xor(bv, off);
            int   oi = __shfl_xor(bi, off);
            if (ov > bv || (ov == bv && oi < bi)) { bv = ov; bi = oi; }
        }
        float cv = (lane == bi) ? -INFINITY : logit;
        int   ci = lane;
        for (int off = 32; off; off >>= 1) {
            float ov = __shfl_xor(cv, off);
            int   oi = __shfl_xor(ci, off);
            if (ov > cv || (ov == cv && oi < ci)) { cv = ov; ci = oi; }
        }

        if (lane == 0) {
            const int gt = tok0 + tl;
            float w0 = 1.f / (1.f + __expf(cv - bv));
            out[(size_t)gt * 2]     = w0;
            out[(size_t)gt * 2 + 1] = 1.f - w0;
            out[(size_t)2 * N + gt * 2]     = (float)bi;
            out[(size_t)2 * N + gt * 2 + 1] = (float)ci;
        }

        pacc += prob;
        facc += (lane == bi ? 1.f : 0.f) + (lane == ci ? 1.f : 0.f);
    }

    p_red[wid][lane] = pacc;
    f_red[wid][lane] = facc;
    __syncthreads();
    if (wid == 0) {
        float sp = 0.f, sf = 0.f;
#pragma unroll
        for (int w = 0; w < 8; ++w) { sp += p_red[w][lane]; sf += f_red[w][lane]; }
        p_part[(size_t)blockIdx.x * NUM_EXP + lane] = sp;
        f_part[(size_t)blockIdx.x * NUM_EXP + lane] = sf;
    }
}

// ---------------------------------------------------------------------------
// k3: deterministic aux-loss reduction over per-block partials.
// aux = E * sum_i (f_sum_i / N) * (p_sum_i / N)
// ---------------------------------------------------------------------------
__global__ __launch_bounds__(1024)
void k3_aux(const float* __restrict__ p_part, const float* __restrict__ f_part,
            float* __restrict__ out, int N, int B2) {
    const int lane = threadIdx.x & 63;
    const int wid  = threadIdx.x >> 6;    // 0..15
    float sp = 0.f, sf = 0.f;
    for (int b = wid; b < B2; b += 16) {
        sp += p_part[(size_t)b * NUM_EXP + lane];
        sf += f_part[(size_t)b * NUM_EXP + lane];
    }
    __shared__ float lsp[16][64];
    __shared__ float lsf[16][64];
    lsp[wid][lane] = sp;
    lsf[wid][lane] = sf;
    __syncthreads();
    if (wid == 0) {
        float tsp = 0.f, tsf = 0.f;
#pragma unroll
        for (int w = 0; w < 16; ++w) { tsp += lsp[w][lane]; tsf += lsf[w][lane]; }
        float v = tsp * tsf;
        for (int off = 32; off; off >>= 1) v += __shfl_xor(v, off);
        if (lane == 0)
            out[(size_t)4 * N] = (float)NUM_EXP * v / ((float)N * (float)N);
    }
}

extern "C" void kernel_launch(void* const* d_in, const int* in_sizes, int n_in,
                              void* d_out, int out_size, void* d_ws, size_t ws_size,
                              hipStream_t stream) {
    const float* x = (const float*)d_in[0];
    const float* W = (const float*)d_in[1];
    float* out = (float*)d_out;

    const int N  = in_sizes[0] / D_MODEL;   // 16384
    const int B1 = N / 64;                  // 256 fused blocks

    // ws layout: [whf 256KB][wlf 256KB][p_part 64KB][f_part 64KB]
    f16x8* whf = (f16x8*)d_ws;
    f16x8* wlf = whf + 16384;
    float* p_part = (float*)(wlf + 16384);
    float* f_part = p_part + (size_t)B1 * NUM_EXP;

    k0_convw<<<64, 256, 0, stream>>>(W, whf, wlf);
    k1_fused<<<B1, 512, 0, stream>>>(x, whf, wlf, out, p_part, f_part, N);
    k3_aux<<<1, 1024, 0, stream>>>(p_part, f_part, out, N, B1);
}